// Round 3
// baseline (175.496 us; speedup 1.0000x reference)
//
#include <hip/hip_runtime.h>

// MultiScaleTrendLoss, exact chunked-scan formulation.
//
// loss = mean_{b,f} sum_a w_a * mean_t EMA_a(pred-target)[b,t,f]^2
// (EMA linearity: EMA(pred)-EMA(target) == EMA(d), d = pred-target, y0 = d0.)
//
// Chunk splicing (exact): for chunk with carry-in e (= y at last t of prev
// chunk), y_t = z_t + r^{k+1} e  (z = zero-carry local EMA, r = 1-alpha,
// k = 0..L-1). Hence sum y^2 over chunk = A + 2 e B + e^2 C with
//   A = sum z^2,  B = sum z r^{k+1},  C = sum_{j=1..L} r^{2j}  (compile-time)
// and carry-out e' = z_end + r^L e.
//
// Pass 1: 64 batches x 32 chunks of 128 steps -> per-(b,f,alpha) stats A,B,Z.
//         Reads every input element exactly once (134 MB total).
// Pass 2: serial splice over 32 chunks per (b,f,alpha) + reduction. Tiny.

#define T_LEN   4096
#define F_LEN   64
#define NB      64
#define NCHUNK  32
#define CHUNK   128
#define NPAIR   (NB * F_LEN)   // 4096

// r^n at compile time (double internally)
constexpr double powd(double r, int n) {
    double v = 1.0, b = r;
    while (n > 0) { if (n & 1) v *= b; b *= b; n >>= 1; }
    return v;
}
constexpr float R0 = 0.9f, R1 = 0.7f, R2 = 0.5f;
constexpr float RL0 = (float)powd(0.9, CHUNK);   // r^L
constexpr float RL1 = (float)powd(0.7, CHUNK);
constexpr float RL2 = (float)powd(0.5, CHUNK);
constexpr float C0 = (float)(0.81 * (1.0 - powd(0.9, 2 * CHUNK)) / (1.0 - 0.81));
constexpr float C1 = (float)(0.49 * (1.0 - powd(0.7, 2 * CHUNK)) / (1.0 - 0.49));
constexpr float C2 = (float)(0.25 * (1.0 - powd(0.5, 2 * CHUNK)) / (1.0 - 0.25));

// ws layout: stat slot s in 0..8  (alpha*3 + {A=0,B=1,Z=2})
//   ws[(s*NCHUNK + c)*NPAIR + b*64 + f]
// total = 9*32*4096 floats = 4.7 MB

__global__ __launch_bounds__(64)
void mstl_pass1(const float* __restrict__ pred,
                const float* __restrict__ targ,
                float* __restrict__ ws)
{
    const int f = threadIdx.x;
    const int b = blockIdx.x >> 5;
    const int c = blockIdx.x & (NCHUNK - 1);

    const float* __restrict__ p = pred + ((size_t)b * T_LEN + c * CHUNK) * F_LEN + f;
    const float* __restrict__ q = targ + ((size_t)b * T_LEN + c * CHUNK) * F_LEN + f;

    float a0 = 0.f, a1 = 0.f, a2 = 0.f;   // A = sum z^2
    float b0 = 0.f, b1 = 0.f, b2 = 0.f;   // B = sum z r^{k+1}
    float z0 = 0.f, z1 = 0.f, z2 = 0.f;   // zero-carry EMA state

    if (c == 0) {
        // exact init y0 = d0; B stays 0 (carry-in is 0 for chunk 0)
        float d = p[0] - q[0];
        z0 = d; z1 = d; z2 = d;
        float dd = d * d;
        a0 = dd; a1 = dd; a2 = dd;
        #pragma unroll 16
        for (int i = 1; i < CHUNK; ++i) {
            float dv = p[(size_t)i * F_LEN] - q[(size_t)i * F_LEN];
            z0 = fmaf(R0, z0, 0.1f * dv);
            z1 = fmaf(R1, z1, 0.3f * dv);
            z2 = fmaf(R2, z2, 0.5f * dv);
            a0 = fmaf(z0, z0, a0);
            a1 = fmaf(z1, z1, a1);
            a2 = fmaf(z2, z2, a2);
        }
    } else {
        float w0 = R0, w1 = R1, w2 = R2;  // r^{k+1}
        #pragma unroll 16
        for (int i = 0; i < CHUNK; ++i) {
            float dv = p[(size_t)i * F_LEN] - q[(size_t)i * F_LEN];
            z0 = fmaf(R0, z0, 0.1f * dv);
            z1 = fmaf(R1, z1, 0.3f * dv);
            z2 = fmaf(R2, z2, 0.5f * dv);
            a0 = fmaf(z0, z0, a0);
            a1 = fmaf(z1, z1, a1);
            a2 = fmaf(z2, z2, a2);
            b0 = fmaf(z0, w0, b0); w0 *= R0;
            b1 = fmaf(z1, w1, b1); w1 *= R1;
            b2 = fmaf(z2, w2, b2); w2 *= R2;
        }
    }

    const int pf = b * F_LEN + f;
    float* w = ws + (size_t)c * NPAIR + pf;
    w[(size_t)(0 * NCHUNK) * NPAIR] = a0;
    w[(size_t)(1 * NCHUNK) * NPAIR] = b0;
    w[(size_t)(2 * NCHUNK) * NPAIR] = z0;
    w[(size_t)(3 * NCHUNK) * NPAIR] = a1;
    w[(size_t)(4 * NCHUNK) * NPAIR] = b1;
    w[(size_t)(5 * NCHUNK) * NPAIR] = z1;
    w[(size_t)(6 * NCHUNK) * NPAIR] = a2;
    w[(size_t)(7 * NCHUNK) * NPAIR] = b2;
    w[(size_t)(8 * NCHUNK) * NPAIR] = z2;
}

__global__ __launch_bounds__(64)
void mstl_pass2(const float* __restrict__ ws, float* __restrict__ out)
{
    const int f = threadIdx.x;
    const int b = blockIdx.x;
    const int pf = b * F_LEN + f;

    float total = 0.f;

    // alpha = 0.1
    {
        float e = 0.f, s = 0.f;
        #pragma unroll 8
        for (int c = 0; c < NCHUNK; ++c) {
            const float* w = ws + (size_t)c * NPAIR + pf;
            float A = w[(size_t)(0 * NCHUNK) * NPAIR];
            float B = w[(size_t)(1 * NCHUNK) * NPAIR];
            float Z = w[(size_t)(2 * NCHUNK) * NPAIR];
            s += A + 2.f * e * B + e * e * C0;
            e = Z + RL0 * e;
        }
        total = fmaf(0.5f, s, total);
    }
    // alpha = 0.3
    {
        float e = 0.f, s = 0.f;
        #pragma unroll 8
        for (int c = 0; c < NCHUNK; ++c) {
            const float* w = ws + (size_t)c * NPAIR + pf;
            float A = w[(size_t)(3 * NCHUNK) * NPAIR];
            float B = w[(size_t)(4 * NCHUNK) * NPAIR];
            float Z = w[(size_t)(5 * NCHUNK) * NPAIR];
            s += A + 2.f * e * B + e * e * C1;
            e = Z + RL1 * e;
        }
        total = fmaf(0.3f, s, total);
    }
    // alpha = 0.5
    {
        float e = 0.f, s = 0.f;
        #pragma unroll 8
        for (int c = 0; c < NCHUNK; ++c) {
            const float* w = ws + (size_t)c * NPAIR + pf;
            float A = w[(size_t)(6 * NCHUNK) * NPAIR];
            float B = w[(size_t)(7 * NCHUNK) * NPAIR];
            float Z = w[(size_t)(8 * NCHUNK) * NPAIR];
            s += A + 2.f * e * B + e * e * C2;
            e = Z + RL2 * e;
        }
        total = fmaf(0.2f, s, total);
    }

    // wave-64 butterfly reduce over features
    #pragma unroll
    for (int off = 32; off > 0; off >>= 1)
        total += __shfl_down(total, off, 64);

    if (f == 0) {
        // mean over T (4096) and over b*f pairs (4096)
        atomicAdd(out, total * (1.0f / 16777216.0f));
    }
}

extern "C" void kernel_launch(void* const* d_in, const int* in_sizes, int n_in,
                              void* d_out, int out_size, void* d_ws, size_t ws_size,
                              hipStream_t stream) {
    const float* pred = (const float*)d_in[0];
    const float* targ = (const float*)d_in[1];
    float* out = (float*)d_out;
    float* ws  = (float*)d_ws;   // needs 9*32*4096*4 = 4.7 MB

    // d_out is poisoned 0xAA before every call -- zero it (atomicAdd target)
    hipMemsetAsync(out, 0, sizeof(float) * out_size, stream);

    mstl_pass1<<<dim3(NB * NCHUNK), dim3(64), 0, stream>>>(pred, targ, ws);
    mstl_pass2<<<dim3(NB), dim3(64), 0, stream>>>(ws, out);
}

// Round 5
// 169.521 us; speedup vs baseline: 1.0352x; 1.0352x over previous
//
#include <hip/hip_runtime.h>

// MultiScaleTrendLoss, exact chunked-scan, explicitly software-pipelined.
//
// loss = mean_{b,f} sum_a w_a * mean_t EMA_a(pred-target)[b,t,f]^2
// EMA linearity: EMA(pred)-EMA(target) == EMA(d), d = pred-target.
//
// Uniform chunk algebra: let z be the zero-init EMA within a chunk
// (z_{-1}=0, z_k = alpha*d_k + r*z_{k-1}).  With carry-in e (= y before the
// chunk), the true y_k = z_k + r^{k+1} e.  Then
//   sum_k y_k^2 = A + 2eB + e^2 C,  A=sum z^2, B=sum z_k r^{k+1},
//   C = r^2(1-r^{2L})/(1-r^2)  (compile-time),  carry-out e' = z_{L-1} + r^L e.
// Chunk 0 with init y_0 = d_0 is EXACTLY the uniform recurrence with
// carry-in e = d_0  (y_t - z_t = r^{t+1} d_0).  So pass1 is branch-free and
// pass2 seeds e from d_0 read straight from pred/targ.
//
// Pass1: each 32-lane half-wave owns one (batch, chunk); float2 loads cover
// the 64-feature row (256B/half-wave, coalesced).  Explicit 2-stage pipeline
// (4 timesteps/stage, named registers) keeps 8 dwordx2 in flight per wave --
// the round-3 kernel had ~1 (VGPR_Count=32, 1.5 TB/s latency-pinned).
// Pass2: 192 waves, one (alpha, 64-pair-block) each; coalesced stat reads.

#define T_LEN 4096
#define F_LEN 64
#define NB    64
#define NPAIR 4096

constexpr double powd(double r, int n) {
    double v = 1.0, b = r;
    while (n > 0) { if (n & 1) v *= b; b *= b; n >>= 1; }
    return v;
}

// ---------------------------------------------------------------- pass 1
template<int NCHUNK>
__global__ __launch_bounds__(64)
void mstl_pass1(const float2* __restrict__ pred,
                const float2* __restrict__ targ,
                float* __restrict__ ws)
{
    constexpr int CHUNK = T_LEN / NCHUNK;
    constexpr int NSTG  = CHUNK / 4;          // 4 timesteps per stage
    constexpr float R0 = 0.9f, R1 = 0.7f, R2 = 0.5f;
    constexpr float A0 = 0.1f, A1 = 0.3f, A2 = 0.5f;

    const int lane = threadIdx.x;
    const int g    = lane >> 5;               // half-wave 0/1
    const int fh   = lane & 31;               // float2 lane within row
    const int task = blockIdx.x * 2 + g;      // (b, c) task
    const int b    = task / NCHUNK;
    const int c    = task % NCHUNK;

    const float2* __restrict__ p = pred + ((size_t)(b * T_LEN + c * CHUNK)) * 32 + fh;
    const float2* __restrict__ q = targ + ((size_t)(b * T_LEN + c * CHUNK)) * 32 + fh;

    float2 z0{0,0}, z1{0,0}, z2{0,0};         // zero-carry EMA state
    float2 a0{0,0}, a1{0,0}, a2{0,0};         // A = sum z^2
    float2 b0{0,0}, b1{0,0}, b2{0,0};         // B = sum z r^{k+1}
    float  w0 = R0, w1 = R1, w2 = R2;         // r^{k+1}

    // named double-buffered stages (static indexing only -- no scratch)
    float2 pA0,pA1,pA2,pA3, qA0,qA1,qA2,qA3;
    float2 pB0,pB1,pB2,pB3, qB0,qB1,qB2,qB3;

#define LOADA(t0) { pA0=p[(size_t)(t0)*32]; pA1=p[(size_t)((t0)+1)*32]; \
                    pA2=p[(size_t)((t0)+2)*32]; pA3=p[(size_t)((t0)+3)*32]; \
                    qA0=q[(size_t)(t0)*32]; qA1=q[(size_t)((t0)+1)*32]; \
                    qA2=q[(size_t)((t0)+2)*32]; qA3=q[(size_t)((t0)+3)*32]; }
#define LOADB(t0) { pB0=p[(size_t)(t0)*32]; pB1=p[(size_t)((t0)+1)*32]; \
                    pB2=p[(size_t)((t0)+2)*32]; pB3=p[(size_t)((t0)+3)*32]; \
                    qB0=q[(size_t)(t0)*32]; qB1=q[(size_t)((t0)+1)*32]; \
                    qB2=q[(size_t)((t0)+2)*32]; qB3=q[(size_t)((t0)+3)*32]; }
#define STEP(pp, qq) { \
    float dx = (pp).x - (qq).x, dy = (pp).y - (qq).y; \
    z0.x = fmaf(R0, z0.x, A0*dx); z0.y = fmaf(R0, z0.y, A0*dy); \
    a0.x = fmaf(z0.x, z0.x, a0.x); a0.y = fmaf(z0.y, z0.y, a0.y); \
    b0.x = fmaf(z0.x, w0, b0.x);   b0.y = fmaf(z0.y, w0, b0.y);   w0 *= R0; \
    z1.x = fmaf(R1, z1.x, A1*dx); z1.y = fmaf(R1, z1.y, A1*dy); \
    a1.x = fmaf(z1.x, z1.x, a1.x); a1.y = fmaf(z1.y, z1.y, a1.y); \
    b1.x = fmaf(z1.x, w1, b1.x);   b1.y = fmaf(z1.y, w1, b1.y);   w1 *= R1; \
    z2.x = fmaf(R2, z2.x, A2*dx); z2.y = fmaf(R2, z2.y, A2*dy); \
    a2.x = fmaf(z2.x, z2.x, a2.x); a2.y = fmaf(z2.y, z2.y, a2.y); \
    b2.x = fmaf(z2.x, w2, b2.x);   b2.y = fmaf(z2.y, w2, b2.y);   w2 *= R2; }
#define COMPA() { STEP(pA0,qA0) STEP(pA1,qA1) STEP(pA2,qA2) STEP(pA3,qA3) }
#define COMPB() { STEP(pB0,qB0) STEP(pB1,qB1) STEP(pB2,qB2) STEP(pB3,qB3) }

    LOADA(0);
    #pragma unroll
    for (int s = 0; s < NSTG; s += 2) {
        LOADB((s + 1) * 4);
        COMPA();
        if (s + 2 < NSTG) LOADA((s + 2) * 4);
        COMPB();
    }
#undef LOADA
#undef LOADB
#undef STEP
#undef COMPA
#undef COMPB

    // store stats: slot s (0..8), layout ws[(s*NCHUNK + c)*NPAIR + pf]
    const int pf = b * F_LEN + fh * 2;
#define ST(slot, val) *(float2*)(ws + ((size_t)(slot) * NCHUNK + c) * NPAIR + pf) = (val);
    ST(0, a0) ST(1, b0) ST(2, z0)
    ST(3, a1) ST(4, b1) ST(5, z1)
    ST(6, a2) ST(7, b2) ST(8, z2)
#undef ST
}

// ---------------------------------------------------------------- pass 2
template<int NCHUNK>
__global__ __launch_bounds__(64)
void mstl_pass2(const float* __restrict__ ws,
                const float* __restrict__ pred,
                const float* __restrict__ targ,
                float* __restrict__ out)
{
    constexpr int CHUNK = T_LEN / NCHUNK;
    constexpr float RL[3] = { (float)powd(0.9, CHUNK), (float)powd(0.7, CHUNK),
                              (float)powd(0.5, CHUNK) };
    constexpr float CC[3] = {
        (float)(0.81 * (1.0 - powd(0.9, 2*CHUNK)) / (1.0 - 0.81)),
        (float)(0.49 * (1.0 - powd(0.7, 2*CHUNK)) / (1.0 - 0.49)),
        (float)(0.25 * (1.0 - powd(0.5, 2*CHUNK)) / (1.0 - 0.25)) };
    constexpr float WGT[3] = { 0.5f, 0.3f, 0.2f };

    const int a   = blockIdx.x >> 6;          // alpha index 0..2 (uniform)
    const int pfb = blockIdx.x & 63;
    const int pf  = pfb * 64 + threadIdx.x;   // (b,f) pair
    const int b   = pf >> 6, f = pf & 63;

    float rl = (a == 0) ? RL[0] : (a == 1) ? RL[1] : RL[2];
    float cc = (a == 0) ? CC[0] : (a == 1) ? CC[1] : CC[2];
    float wg = (a == 0) ? WGT[0] : (a == 1) ? WGT[1] : WGT[2];

    // carry-in for chunk 0 is d_0 (uniform-recurrence identity)
    const size_t row0 = (size_t)b * T_LEN * F_LEN + f;
    float e = pred[row0] - targ[row0];

    const float* __restrict__ base = ws + (size_t)(a * 3) * NCHUNK * NPAIR + pf;

    float s = 0.f;
    #pragma unroll 8
    for (int c = 0; c < NCHUNK; ++c) {
        float A = base[((size_t)0 * NCHUNK + c) * NPAIR];
        float B = base[((size_t)1 * NCHUNK + c) * NPAIR];
        float Z = base[((size_t)2 * NCHUNK + c) * NPAIR];
        s += A + e * (2.f * B + e * cc);
        e = fmaf(rl, e, Z);
    }

    float total = s * wg;
    #pragma unroll
    for (int off = 32; off > 0; off >>= 1)
        total += __shfl_down(total, off, 64);

    if (threadIdx.x == 0)
        atomicAdd(out, total * (1.0f / 16777216.0f));   // / (T * B * F)
}

// ---------------------------------------------------------------- launch
extern "C" void kernel_launch(void* const* d_in, const int* in_sizes, int n_in,
                              void* d_out, int out_size, void* d_ws, size_t ws_size,
                              hipStream_t stream) {
    const float* pred = (const float*)d_in[0];
    const float* targ = (const float*)d_in[1];
    float* out = (float*)d_out;
    float* ws  = (float*)d_ws;

    hipMemsetAsync(out, 0, sizeof(float) * out_size, stream);

    const size_t need64 = (size_t)9 * 64 * NPAIR * sizeof(float);  // 9.44 MB
    if (ws_size >= need64) {
        mstl_pass1<64><<<dim3(NB * 64 / 2), dim3(64), 0, stream>>>(
            (const float2*)pred, (const float2*)targ, ws);
        mstl_pass2<64><<<dim3(192), dim3(64), 0, stream>>>(ws, pred, targ, out);
    } else {  // proven 4.72 MB footprint fallback
        mstl_pass1<32><<<dim3(NB * 32 / 2), dim3(64), 0, stream>>>(
            (const float2*)pred, (const float2*)targ, ws);
        mstl_pass2<32><<<dim3(192), dim3(64), 0, stream>>>(ws, pred, targ, out);
    }
}

// Round 6
// 166.443 us; speedup vs baseline: 1.0544x; 1.0185x over previous
//
#include <hip/hip_runtime.h>

// MultiScaleTrendLoss, exact chunked-scan, float4-per-lane pass1.
//
// loss = mean_{b,f} sum_a w_a * mean_t EMA_a(pred-target)[b,t,f]^2
// EMA linearity: EMA(pred)-EMA(target) == EMA(d), d = pred-target.
//
// Chunk algebra (exact, proven absmax=0 in rounds 3/5): z = zero-init EMA
// within chunk; with carry-in e, y_k = z_k + r^{k+1} e, so
//   sum y^2 = A + 2eB + e^2 C,  A=sum z^2, B=sum z_k r^{k+1},
//   C=r^2(1-r^{2L})/(1-r^2),  carry-out e' = z_{L-1} + r^L e.
// Chunk 0 (y_0 = d_0) == uniform recurrence with carry-in e = d_0.
//
// Round-5 lesson: float/float2 loads plateau at ~1.5-2.4 TB/s regardless of
// software pipelining -- per-CU outstanding-line budget (~8-9 KB, per m13
// float4-copy 6.29 TB/s) is only filled by 16 B/lane loads.  Pass1 lane
// layout: g = lane>>4 selects one of 4 chunk-tasks, fl = lane&15 selects a
// feature quad; each lane float4-loads 4 features and runs 4 EMA chains.
// 2-stage x 4-timestep named pipeline = 8 float4-pairs (8 KB) in flight.

#define T_LEN 4096
#define F_LEN 64
#define NB    64
#define NPAIR 4096

constexpr double powd(double r, int n) {
    double v = 1.0, b = r;
    while (n > 0) { if (n & 1) v *= b; b *= b; n >>= 1; }
    return v;
}

// ---------------------------------------------------------------- pass 1
template<int NCHUNK>
__global__ __launch_bounds__(64)
void mstl_pass1(const float4* __restrict__ pred,
                const float4* __restrict__ targ,
                float* __restrict__ ws)
{
    constexpr int CHUNK = T_LEN / NCHUNK;
    constexpr int NSTG  = CHUNK / 4;          // 4 timesteps per stage
    constexpr float R0 = 0.9f, R1 = 0.7f, R2 = 0.5f;
    constexpr float A0 = 0.1f, A1 = 0.3f, A2 = 0.5f;

    const int lane = threadIdx.x;
    const int g    = lane >> 4;               // task slot 0..3
    const int fl   = lane & 15;               // feature quad (4*fl..4*fl+3)
    const int task = blockIdx.x * 4 + g;
    const int b    = task / NCHUNK;
    const int c    = task % NCHUNK;

    // row of 64 floats = 16 float4; lane fl covers its quad
    const float4* __restrict__ p = pred + (size_t)(b * T_LEN + c * CHUNK) * 16 + fl;
    const float4* __restrict__ q = targ + (size_t)(b * T_LEN + c * CHUNK) * 16 + fl;

    float4 z0{0,0,0,0}, z1{0,0,0,0}, z2{0,0,0,0};
    float4 a0{0,0,0,0}, a1{0,0,0,0}, a2{0,0,0,0};
    float4 b0{0,0,0,0}, b1{0,0,0,0}, b2{0,0,0,0};
    float  w0 = R0, w1 = R1, w2 = R2;         // r^{k+1}

    float4 pA0,pA1,pA2,pA3, qA0,qA1,qA2,qA3;  // named stages, static idx only
    float4 pB0,pB1,pB2,pB3, qB0,qB1,qB2,qB3;

#define LOADA(t0) { pA0=p[(size_t)(t0)*16];     pA1=p[(size_t)((t0)+1)*16]; \
                    pA2=p[(size_t)((t0)+2)*16]; pA3=p[(size_t)((t0)+3)*16]; \
                    qA0=q[(size_t)(t0)*16];     qA1=q[(size_t)((t0)+1)*16]; \
                    qA2=q[(size_t)((t0)+2)*16]; qA3=q[(size_t)((t0)+3)*16]; }
#define LOADB(t0) { pB0=p[(size_t)(t0)*16];     pB1=p[(size_t)((t0)+1)*16]; \
                    pB2=p[(size_t)((t0)+2)*16]; pB3=p[(size_t)((t0)+3)*16]; \
                    qB0=q[(size_t)(t0)*16];     qB1=q[(size_t)((t0)+1)*16]; \
                    qB2=q[(size_t)((t0)+2)*16]; qB3=q[(size_t)((t0)+3)*16]; }
#define STEP(P,Q) { \
    const float dx=(P).x-(Q).x, dy=(P).y-(Q).y, dz=(P).z-(Q).z, dw=(P).w-(Q).w; \
    z0.x=fmaf(R0,z0.x,A0*dx); a0.x=fmaf(z0.x,z0.x,a0.x); b0.x=fmaf(z0.x,w0,b0.x); \
    z0.y=fmaf(R0,z0.y,A0*dy); a0.y=fmaf(z0.y,z0.y,a0.y); b0.y=fmaf(z0.y,w0,b0.y); \
    z0.z=fmaf(R0,z0.z,A0*dz); a0.z=fmaf(z0.z,z0.z,a0.z); b0.z=fmaf(z0.z,w0,b0.z); \
    z0.w=fmaf(R0,z0.w,A0*dw); a0.w=fmaf(z0.w,z0.w,a0.w); b0.w=fmaf(z0.w,w0,b0.w); \
    w0 *= R0; \
    z1.x=fmaf(R1,z1.x,A1*dx); a1.x=fmaf(z1.x,z1.x,a1.x); b1.x=fmaf(z1.x,w1,b1.x); \
    z1.y=fmaf(R1,z1.y,A1*dy); a1.y=fmaf(z1.y,z1.y,a1.y); b1.y=fmaf(z1.y,w1,b1.y); \
    z1.z=fmaf(R1,z1.z,A1*dz); a1.z=fmaf(z1.z,z1.z,a1.z); b1.z=fmaf(z1.z,w1,b1.z); \
    z1.w=fmaf(R1,z1.w,A1*dw); a1.w=fmaf(z1.w,z1.w,a1.w); b1.w=fmaf(z1.w,w1,b1.w); \
    w1 *= R1; \
    z2.x=fmaf(R2,z2.x,A2*dx); a2.x=fmaf(z2.x,z2.x,a2.x); b2.x=fmaf(z2.x,w2,b2.x); \
    z2.y=fmaf(R2,z2.y,A2*dy); a2.y=fmaf(z2.y,z2.y,a2.y); b2.y=fmaf(z2.y,w2,b2.y); \
    z2.z=fmaf(R2,z2.z,A2*dz); a2.z=fmaf(z2.z,z2.z,a2.z); b2.z=fmaf(z2.z,w2,b2.z); \
    z2.w=fmaf(R2,z2.w,A2*dw); a2.w=fmaf(z2.w,z2.w,a2.w); b2.w=fmaf(z2.w,w2,b2.w); \
    w2 *= R2; }
#define COMPA() { STEP(pA0,qA0) STEP(pA1,qA1) STEP(pA2,qA2) STEP(pA3,qA3) }
#define COMPB() { STEP(pB0,qB0) STEP(pB1,qB1) STEP(pB2,qB2) STEP(pB3,qB3) }

    LOADA(0);
    #pragma unroll
    for (int s = 0; s < NSTG; s += 2) {
        LOADB((s + 1) * 4);
        COMPA();
        if (s + 2 < NSTG) LOADA((s + 2) * 4);
        COMPB();
    }
#undef LOADA
#undef LOADB
#undef STEP
#undef COMPA
#undef COMPB

    // stats: slot s in 0..8, layout ws[(s*NCHUNK + c)*NPAIR + b*64 + 4*fl]
    const int pf = b * F_LEN + fl * 4;        // 16 B aligned
#define ST(slot, val) *(float4*)(ws + ((size_t)(slot) * NCHUNK + c) * NPAIR + pf) = (val);
    ST(0, a0) ST(1, b0) ST(2, z0)
    ST(3, a1) ST(4, b1) ST(5, z1)
    ST(6, a2) ST(7, b2) ST(8, z2)
#undef ST
}

// ---------------------------------------------------------------- pass 2
template<int NCHUNK>
__global__ __launch_bounds__(64)
void mstl_pass2(const float* __restrict__ ws,
                const float* __restrict__ pred,
                const float* __restrict__ targ,
                float* __restrict__ out)
{
    constexpr int CHUNK = T_LEN / NCHUNK;
    constexpr float RL[3] = { (float)powd(0.9, CHUNK), (float)powd(0.7, CHUNK),
                              (float)powd(0.5, CHUNK) };
    constexpr float CC[3] = {
        (float)(0.81 * (1.0 - powd(0.9, 2*CHUNK)) / (1.0 - 0.81)),
        (float)(0.49 * (1.0 - powd(0.7, 2*CHUNK)) / (1.0 - 0.49)),
        (float)(0.25 * (1.0 - powd(0.5, 2*CHUNK)) / (1.0 - 0.25)) };
    constexpr float WGT[3] = { 0.5f, 0.3f, 0.2f };

    const int a   = blockIdx.x >> 6;          // alpha index (block-uniform)
    const int pfb = blockIdx.x & 63;
    const int pf  = pfb * 64 + threadIdx.x;   // (b,f) pair
    const int b   = pf >> 6, f = pf & 63;

    const float rl = (a == 0) ? RL[0] : (a == 1) ? RL[1] : RL[2];
    const float cc = (a == 0) ? CC[0] : (a == 1) ? CC[1] : CC[2];
    const float wg = (a == 0) ? WGT[0] : (a == 1) ? WGT[1] : WGT[2];

    // carry-in for chunk 0 is d_0
    const size_t row0 = (size_t)b * T_LEN * F_LEN + f;
    float e = pred[row0] - targ[row0];

    const float* __restrict__ base = ws + (size_t)(a * 3) * NCHUNK * NPAIR + pf;

    float s = 0.f;
    #pragma unroll 16
    for (int c = 0; c < NCHUNK; ++c) {
        float A = base[((size_t)0 * NCHUNK + c) * NPAIR];
        float B = base[((size_t)1 * NCHUNK + c) * NPAIR];
        float Z = base[((size_t)2 * NCHUNK + c) * NPAIR];
        s += A + e * (2.f * B + e * cc);
        e = fmaf(rl, e, Z);
    }

    float total = s * wg;
    #pragma unroll
    for (int off = 32; off > 0; off >>= 1)
        total += __shfl_down(total, off, 64);

    if (threadIdx.x == 0)
        atomicAdd(out, total * (1.0f / 16777216.0f));   // / (T * B * F)
}

// ---------------------------------------------------------------- launch
extern "C" void kernel_launch(void* const* d_in, const int* in_sizes, int n_in,
                              void* d_out, int out_size, void* d_ws, size_t ws_size,
                              hipStream_t stream) {
    const float* pred = (const float*)d_in[0];
    const float* targ = (const float*)d_in[1];
    float* out = (float*)d_out;
    float* ws  = (float*)d_ws;

    hipMemsetAsync(out, 0, sizeof(float) * out_size, stream);

    const size_t need64 = (size_t)9 * 64 * NPAIR * sizeof(float);  // 9.44 MB
    if (ws_size >= need64) {
        mstl_pass1<64><<<dim3(NB * 64 / 4), dim3(64), 0, stream>>>(
            (const float4*)pred, (const float4*)targ, ws);
        mstl_pass2<64><<<dim3(192), dim3(64), 0, stream>>>(ws, pred, targ, out);
    } else {  // 4.72 MB footprint fallback
        mstl_pass1<32><<<dim3(NB * 32 / 4), dim3(64), 0, stream>>>(
            (const float4*)pred, (const float4*)targ, ws);
        mstl_pass2<32><<<dim3(192), dim3(64), 0, stream>>>(ws, pred, targ, out);
    }
}